// Round 9
// baseline (140.013 us; speedup 1.0000x reference)
//
#include <hip/hip_runtime.h>
#include <hip/hip_bf16.h>

#define BATCH 32
#define LL 512
#define DD 768
#define EPSC 1e-5f

typedef __attribute__((ext_vector_type(8))) short bf16x8;
typedef __attribute__((ext_vector_type(4))) float f32x4;

// ---------------------------------------------------------------------------
// Kernel 1 (fused prep): block = (l-block of 64 rows, batch). Phase 1 computes
// w[l] = (eps + sum_d x^2)^(1/4) in-register (4 lanes per row, 2 shfl).
// Phase 2 = the harness-verified 64x64 LDS transpose body, iterated over the
// 12 d-tiles (x re-reads come from L2). ~12 us = its 75 MB HBM floor.
// ---------------------------------------------------------------------------
__global__ __launch_bounds__(256) void k_prep(const float* __restrict__ x,
                                              ushort* __restrict__ yt) {
    __shared__ float tile[64][65];
    __shared__ float svec[64];
    int lb = blockIdx.x;                              // [0,8) l-block
    int b = blockIdx.y;
    int l0 = lb * 64;
    int t = threadIdx.x;

    // Phase 1: row r = t>>2 (0..63), quarter q = t&3 covers 192 floats.
    {
        int r = t >> 2, q = t & 3;
        const float4* xr = (const float4*)(x + ((size_t)b * LL + l0 + r) * DD) + q * 48;
        float sum = 0.f;
#pragma unroll 8
        for (int i = 0; i < 48; i++) {
            float4 v = xr[i];
            sum += v.x * v.x + v.y * v.y + v.z * v.z + v.w * v.w;
        }
        sum += __shfl_xor(sum, 1, 64);
        sum += __shfl_xor(sum, 2, 64);
        if (q == 0) svec[r] = sqrtf(sqrtf(EPSC + sum));
    }
    __syncthreads();

    // Phase 2: 12 x (load 64x64 tile -> transpose+scale -> bf16 store).
    const float* xb = x + ((size_t)b * LL + l0) * DD;
    int f = t & 15, lr0 = t >> 4;                     // f: float4 col, lr0: row
    int lc = t & 7, dl0 = t >> 3;                     // lc: l-chunk, dl0: d row
    for (int dt = 0; dt < 12; dt++) {
        int d0 = dt * 64;
#pragma unroll
        for (int r = 0; r < 4; r++) {
            int l = lr0 + r * 16;
            float4 v = *(const float4*)(xb + (size_t)l * DD + d0 + f * 4);
#pragma unroll
            for (int j = 0; j < 4; j++)
                tile[l][f * 4 + j] = ((const float*)&v)[j];
        }
        __syncthreads();
        ushort* yp = yt + ((size_t)b * DD + d0) * LL + l0;
#pragma unroll
        for (int it = 0; it < 2; it++) {
            int d = dl0 + it * 32;
            bf16x8 w;
#pragma unroll
            for (int j = 0; j < 8; j++) {
                int l = lc * 8 + j;
                float v = tile[l][d] * svec[l];
                __hip_bfloat16 h = __float2bfloat16(v);
                w[j] = *(short*)&h;
            }
            *(bf16x8*)(yp + (size_t)d * LL + lc * 8) = w;
        }
        __syncthreads();
    }
}

// ---------------------------------------------------------------------------
// Kernel 2: C[b] = Yt[b]*Yt[b]^T, symmetric. ONE WAVE PER BLOCK, 64x64 tile
// (acc[4][4] -- R8's 0.5 read:MFMA ratio), wave-private double-buffered LDS
// (2 x 8 KB), ZERO barriers: the wave stages its own panels via
// global_load_lds and syncs with counted `s_waitcnt vmcnt(8)` (inline asm +
// sched_barrier, rule #18). No __syncthreads => no structural vmcnt(0) drain;
// all hazards wave-local (frags are lgkm-consumed by MFMA before next stage).
// B always staged (uniform vmcnt; diag stages duplicate data). 16 KB LDS,
// ~125 VGPR -> ~8-10 blocks/CU vs 9.75 demand (near-zero tail).
// Swizzle: phys chunk pc of row r holds logical chunk pc^(r&3); stage source
// pre-swizzled (linear LDS dest), frag read applies same XOR (rule #21).
// ---------------------------------------------------------------------------
__global__ __launch_bounds__(64) void k_gemm(const ushort* __restrict__ yt,
                                             float* __restrict__ out) {
    __shared__ ushort At[2][64 * 32];                 // 2 x 4 KB
    __shared__ ushort Bt[2][64 * 32];
    int i = blockIdx.x;                               // [0, 2496)
    int xcd = i & 7, slot = i >> 3;                   // batch -> XCD pinning
    int b = xcd + 8 * (slot / 78);
    int p = slot % 78;
    int t = p, tm = 0, rem = 12;
    while (t >= rem) { t -= rem; rem--; tm++; }
    int tn = tm + t;                                  // tm <= tn
    bool diag = (tm == tn);
    int m0 = tm * 64, n0 = tn * 64;
    int lane = threadIdx.x;
    int fr = lane & 15, ks4 = lane >> 4;
    const ushort* yb = yt + (size_t)b * DD * LL;

    // Staging: 4 issues per matrix per buffer; 16B-slot s = is*64+lane:
    // row = s>>2, phys chunk = s&3, logical chunk = (s&3)^(row&3).
    const ushort* gA[4];
    int dBA = (n0 - m0) * LL;                         // B rows offset
#pragma unroll
    for (int is = 0; is < 4; is++) {
        int s = is * 64 + lane;
        int row = s >> 2;
        int lc = (s & 3) ^ (row & 3);
        gA[is] = yb + (size_t)(m0 + row) * LL + lc * 8;
    }

    f32x4 acc[4][4];
#pragma unroll
    for (int ii = 0; ii < 4; ii++)
#pragma unroll
        for (int j = 0; j < 4; j++) acc[ii][j] = (f32x4){0.f, 0.f, 0.f, 0.f};

#define STAGE(buf, ks) do {                                                   \
        int k0_ = (ks) * 32;                                                  \
        _Pragma("unroll")                                                     \
        for (int is = 0; is < 4; is++)                                        \
            __builtin_amdgcn_global_load_lds(                                 \
                (const __attribute__((address_space(1))) void*)(gA[is] + k0_),\
                (__attribute__((address_space(3))) void*)(At[buf] + is * 512),\
                16, 0, 0);                                                    \
        _Pragma("unroll")                                                     \
        for (int is = 0; is < 4; is++)                                        \
            __builtin_amdgcn_global_load_lds(                                 \
                (const __attribute__((address_space(1))) void*)(gA[is] + dBA + k0_),\
                (__attribute__((address_space(3))) void*)(Bt[buf] + is * 512),\
                16, 0, 0);                                                    \
    } while (0)

    STAGE(0, 0);                                      // 8 loads in flight
    for (int ks = 0; ks < 16; ks++) {
        int cur = ks & 1;
        if (ks < 15) {
            STAGE(cur ^ 1, ks + 1);                   // 8 newer in flight
            asm volatile("s_waitcnt vmcnt(8)" ::: "memory");  // drain stage(ks)
        } else {
            asm volatile("s_waitcnt vmcnt(0)" ::: "memory");
        }
        __builtin_amdgcn_sched_barrier(0);
        const ushort* Ab = At[cur];
        const ushort* Bb = Bt[cur];
        bf16x8 af[4], bg[4];
#pragma unroll
        for (int ii = 0; ii < 4; ii++) {
            int mr = ii * 16 + fr;
            int ca = ks4 ^ (mr & 3);
            af[ii] = *(const bf16x8*)(Ab + mr * 32 + ca * 8);
            bg[ii] = *(const bf16x8*)(Bb + mr * 32 + ca * 8);
        }
#pragma unroll
        for (int ii = 0; ii < 4; ii++)
#pragma unroll
            for (int j = 0; j < 4; j++)
                acc[ii][j] = __builtin_amdgcn_mfma_f32_16x16x32_bf16(
                    af[ii], bg[j], acc[ii][j], 0, 0, 0);
    }
#undef STAGE

    // Epilogue (R2/R7-proven). C/D layout: col = lane&15, row = (lane>>4)*4+r.
    // Mirror (transposed) write float4; direct write scalar (off-diag only).
    float* op = out + (size_t)b * DD * DD;
#pragma unroll
    for (int ii = 0; ii < 4; ii++) {
        int colb = m0 + ii * 16 + ks4 * 4;
#pragma unroll
        for (int j = 0; j < 4; j++) {
            int row = n0 + j * 16 + fr;
            float4 v = {acc[ii][j][0], acc[ii][j][1], acc[ii][j][2], acc[ii][j][3]};
            *(float4*)(op + (size_t)row * DD + colb) = v;   // mirror (or diag)
        }
    }
    if (!diag) {
#pragma unroll
        for (int ii = 0; ii < 4; ii++) {
            int mbase = m0 + ii * 16 + ks4 * 4;
#pragma unroll
            for (int j = 0; j < 4; j++) {
                int n = n0 + j * 16 + fr;
#pragma unroll
                for (int r = 0; r < 4; r++)
                    op[(size_t)(mbase + r) * DD + n] = acc[ii][j][r];
            }
        }
    }
}

// ---------------------------------------------------------------------------
extern "C" void kernel_launch(void* const* d_in, const int* in_sizes, int n_in,
                              void* d_out, int out_size, void* d_ws, size_t ws_size,
                              hipStream_t stream) {
    const float* x = (const float*)d_in[0];
    ushort* yt = (ushort*)d_ws;                                     // 25.2 MB bf16

    k_prep<<<dim3(LL / 64, BATCH), 256, 0, stream>>>(x, yt);
    k_gemm<<<dim3(78 * BATCH), 64, 0, stream>>>(yt, (float*)d_out);
}